// Round 1
// baseline (726.831 us; speedup 1.0000x reference)
//
#include <hip/hip_runtime.h>

#define Bv 4
#define Lv 1024
#define Ev 256
#define Hv 8
#define DHv 32

// ---------------------------------------------------------------------------
// GEMM: C[r0:r0+64, c0:c0+64] = A @ W^T + b, for one of up to 3 weight sets.
// blockIdx.x = row tile (4096/64 = 64); blockIdx.y = g*4 + coltile.
// 256 threads, 4x4 micro-tile. LDS tiles transposed [k][col] for vector reads,
// with a (k>>3)-XOR column swizzle to break the 4-way store conflict.
// ---------------------------------------------------------------------------
__global__ __launch_bounds__(256) void gemm_fused(
    const float* __restrict__ A,
    const float* __restrict__ W0, const float* __restrict__ b0, float* __restrict__ C0,
    const float* __restrict__ W1, const float* __restrict__ b1, float* __restrict__ C1,
    const float* __restrict__ W2, const float* __restrict__ b2, float* __restrict__ C2) {
    __shared__ float Xs[32][68];
    __shared__ float Ws[32][68];
    const int g = blockIdx.y >> 2;
    const float* __restrict__ W    = (g == 0) ? W0 : (g == 1) ? W1 : W2;
    const float* __restrict__ bias = (g == 0) ? b0 : (g == 1) ? b1 : b2;
    float* __restrict__ C          = (g == 0) ? C0 : (g == 1) ? C1 : C2;

    const int row0 = blockIdx.x * 64;
    const int col0 = (blockIdx.y & 3) * 64;
    const int t = threadIdx.x;
    const int tx = t & 15, ty = t >> 4;          // 4x4 micro-tile coords
    const int lr = t >> 3;                       // staging: row/col 0..31
    const int lk = (t & 7) * 4;                  // staging: k offset 0..28
    // store-side xor swizzle; (lk+j)>>3 is constant over j=0..3 since lk%4==0
    const int xsw = 4 * ((lk >> 3) & 3);
    const int xa = lr ^ xsw;

    float acc[4][4] = {};

    for (int k0 = 0; k0 < 256; k0 += 32) {
        const float4 a0 = *(const float4*)&A[(size_t)(row0 + lr) * 256 + k0 + lk];
        const float4 a1 = *(const float4*)&A[(size_t)(row0 + 32 + lr) * 256 + k0 + lk];
        const float4 w0 = *(const float4*)&W[(size_t)(col0 + lr) * 256 + k0 + lk];
        const float4 w1 = *(const float4*)&W[(size_t)(col0 + 32 + lr) * 256 + k0 + lk];
        Xs[lk + 0][xa] = a0.x; Xs[lk + 1][xa] = a0.y;
        Xs[lk + 2][xa] = a0.z; Xs[lk + 3][xa] = a0.w;
        Xs[lk + 0][32 + xa] = a1.x; Xs[lk + 1][32 + xa] = a1.y;
        Xs[lk + 2][32 + xa] = a1.z; Xs[lk + 3][32 + xa] = a1.w;
        Ws[lk + 0][xa] = w0.x; Ws[lk + 1][xa] = w0.y;
        Ws[lk + 2][xa] = w0.z; Ws[lk + 3][xa] = w0.w;
        Ws[lk + 0][32 + xa] = w1.x; Ws[lk + 1][32 + xa] = w1.y;
        Ws[lk + 2][32 + xa] = w1.z; Ws[lk + 3][32 + xa] = w1.w;
        __syncthreads();

        #pragma unroll
        for (int kk = 0; kk < 32; ++kk) {
            const int s = (kk >> 3) & 3;
            const float4 av = *(const float4*)&Xs[kk][(ty ^ s) * 4];
            const float4 bv = *(const float4*)&Ws[kk][(tx ^ s) * 4];
            acc[0][0] = fmaf(av.x, bv.x, acc[0][0]);
            acc[0][1] = fmaf(av.x, bv.y, acc[0][1]);
            acc[0][2] = fmaf(av.x, bv.z, acc[0][2]);
            acc[0][3] = fmaf(av.x, bv.w, acc[0][3]);
            acc[1][0] = fmaf(av.y, bv.x, acc[1][0]);
            acc[1][1] = fmaf(av.y, bv.y, acc[1][1]);
            acc[1][2] = fmaf(av.y, bv.z, acc[1][2]);
            acc[1][3] = fmaf(av.y, bv.w, acc[1][3]);
            acc[2][0] = fmaf(av.z, bv.x, acc[2][0]);
            acc[2][1] = fmaf(av.z, bv.y, acc[2][1]);
            acc[2][2] = fmaf(av.z, bv.z, acc[2][2]);
            acc[2][3] = fmaf(av.z, bv.w, acc[2][3]);
            acc[3][0] = fmaf(av.w, bv.x, acc[3][0]);
            acc[3][1] = fmaf(av.w, bv.y, acc[3][1]);
            acc[3][2] = fmaf(av.w, bv.z, acc[3][2]);
            acc[3][3] = fmaf(av.w, bv.w, acc[3][3]);
        }
        __syncthreads();
    }

    const float4 bv4 = *(const float4*)&bias[col0 + tx * 4];
    #pragma unroll
    for (int r = 0; r < 4; ++r) {
        const int row = row0 + ty * 4 + r;
        float4 o;
        o.x = acc[r][0] + bv4.x; o.y = acc[r][1] + bv4.y;
        o.z = acc[r][2] + bv4.z; o.w = acc[r][3] + bv4.w;
        *(float4*)&C[(size_t)row * 256 + col0 + tx * 4] = o;
    }
}

// ---------------------------------------------------------------------------
// Sparse attention: one block per (b, n), 256 threads, SINGLE pass.
// Compact all active m's (<=1024), one plain softmax (no online merges):
// 4 syncthreads total instead of 20. Q fragments hoisted to registers.
// ---------------------------------------------------------------------------
__global__ __launch_bounds__(256) void attn_sparse(const float* __restrict__ Qb,
                                                   const float* __restrict__ Kb,
                                                   const float* __restrict__ Vb,
                                                   const int* __restrict__ adj,
                                                   const float* __restrict__ KE,
                                                   float* __restrict__ AT) {
    __shared__ float Qs[Hv][36];                 // padded: (4h+4j)%32 spread
    __shared__ float S[Hv][1028];                // padded: (4h+ei)%32 spread
    __shared__ int idxm[Lv];
    __shared__ int cnt_s;
    __shared__ float lh[Hv];

    const int bid = blockIdx.x;
    const int b = bid >> 10;
    const int n = bid & 1023;
    const int t = threadIdx.x;
    const int lane = t & 63;
    const size_t nrow = (size_t)(b * Lv + n) * Lv;

    Qs[t >> 5][t & 31] = Qb[(size_t)(b * Lv + n) * Ev + t] * 0.0625f;  // 1/sqrt(256)
    if (t == 0) cnt_s = 0;
    __syncthreads();

    // --- compaction of all active m's (wave ballot + LDS base) ---
    #pragma unroll
    for (int c = 0; c < 4; ++c) {
        const int m = c * 256 + t;
        const bool p = adj[nrow + m] != 0;
        const unsigned long long mask = __ballot(p);
        const int prefix = __popcll(mask & ((1ull << lane) - 1ull));
        int base = 0;
        if (lane == 0) base = atomicAdd(&cnt_s, __popcll(mask));
        base = __shfl(base, 0, 64);
        if (p) idxm[base + prefix] = m;
    }
    __syncthreads();
    const int cnt = cnt_s;

    // --- scores for (entry, head) tasks; head is loop-invariant per thread ---
    {
        const int h = t & 7;
        float4 qf[8];
        #pragma unroll
        for (int j = 0; j < 8; ++j) qf[j] = *(const float4*)&Qs[h][j * 4];
        const float4* __restrict__ K4 = (const float4*)Kb;
        const float4* __restrict__ KE4 = (const float4*)KE;
        const int nt = cnt * 8;
        for (int task = t; task < nt; task += 256) {
            const int ei = task >> 3;
            const int mm = idxm[ei];
            const float4* kp = K4 + (((size_t)(b * Lv + mm)) << 6) + (h << 3);
            const float4* kep = KE4 + ((nrow + mm) << 3);
            float dot = 0.f;
            #pragma unroll
            for (int j = 0; j < 8; ++j) {
                const float4 kv = kp[j], kf = kep[j], qv = qf[j];
                dot = fmaf(qv.x, kv.x + kf.x, dot);
                dot = fmaf(qv.y, kv.y + kf.y, dot);
                dot = fmaf(qv.z, kv.z + kf.z, dot);
                dot = fmaf(qv.w, kv.w + kf.w, dot);
            }
            S[h][ei] = dot;
        }
    }
    __syncthreads();

    // --- plain softmax: 32 threads per head (diag guarantees cnt >= 1) ---
    {
        const int h = t >> 5, d = t & 31;
        float cmax = -1e30f;
        for (int i = d; i < cnt; i += 32) cmax = fmaxf(cmax, S[h][i]);
        #pragma unroll
        for (int off = 16; off >= 1; off >>= 1)
            cmax = fmaxf(cmax, __shfl_xor(cmax, off, 64));
        float csum = 0.f;
        for (int i = d; i < cnt; i += 32) {
            const float pz = __expf(S[h][i] - cmax);
            S[h][i] = pz;
            csum += pz;
        }
        #pragma unroll
        for (int off = 16; off >= 1; off >>= 1)
            csum += __shfl_xor(csum, off, 64);
        if (d == 0) lh[h] = csum;
    }
    __syncthreads();

    // --- PV accumulate: thread t owns output element e = t ---
    {
        const int h = t >> 5;
        const float* __restrict__ vcol = Vb + (size_t)b * Lv * Ev + t;
        float acc = 0.f;
        int i = 0;
        for (; i + 4 <= cnt; i += 4) {
            const int m0 = idxm[i], m1 = idxm[i + 1], m2 = idxm[i + 2], m3 = idxm[i + 3];
            const float p0 = S[h][i],     p1 = S[h][i + 1];
            const float p2 = S[h][i + 2], p3 = S[h][i + 3];
            const float v0 = vcol[(size_t)m0 * Ev];
            const float v1 = vcol[(size_t)m1 * Ev];
            const float v2 = vcol[(size_t)m2 * Ev];
            const float v3 = vcol[(size_t)m3 * Ev];
            acc = fmaf(p0, v0, acc);
            acc = fmaf(p1, v1, acc);
            acc = fmaf(p2, v2, acc);
            acc = fmaf(p3, v3, acc);
        }
        for (; i < cnt; ++i)
            acc = fmaf(S[h][i], vcol[(size_t)idxm[i] * Ev], acc);
        AT[(size_t)(b * Lv + n) * Ev + t] = acc / lh[h];
    }
}

// ---------------------------------------------------------------------------
extern "C" void kernel_launch(void* const* d_in, const int* in_sizes, int n_in,
                              void* d_out, int out_size, void* d_ws, size_t ws_size,
                              hipStream_t stream) {
    const float* X   = (const float*)d_in[0];
    const int*   adj = (const int*)d_in[1];
    const float* KE  = (const float*)d_in[2];
    const float* Wq  = (const float*)d_in[3];
    const float* bq  = (const float*)d_in[4];
    const float* Wk  = (const float*)d_in[5];
    const float* bk  = (const float*)d_in[6];
    const float* Wv  = (const float*)d_in[7];
    const float* bv  = (const float*)d_in[8];
    const float* Wo  = (const float*)d_in[9];
    const float* bo  = (const float*)d_in[10];

    const size_t NE = (size_t)Bv * Lv * Ev;   // 1M floats = 4MB
    float* Qb = (float*)d_ws;
    float* Kb = Qb + NE;
    float* Vb = Kb + NE;
    float* AT = Vb + NE;
    float* out = (float*)d_out;

    const dim3 blk(256);

    // fused Q/K/V projections: 64 row-tiles x (3 mats x 4 col-tiles)
    hipLaunchKernelGGL(gemm_fused, dim3(64, 12), blk, 0, stream, X,
                       Wq, bq, Qb, Wk, bk, Kb, Wv, bv, Vb);
    hipLaunchKernelGGL(attn_sparse, dim3(Bv * Lv), blk, 0, stream,
                       Qb, Kb, Vb, adj, KE, AT);
    // output projection (g is always 0)
    hipLaunchKernelGGL(gemm_fused, dim3(64, 4), blk, 0, stream, AT,
                       Wo, bo, out, Wo, bo, out, Wo, bo, out);
}